// Round 10
// baseline (400.993 us; speedup 1.0000x reference)
//
#include <hip/hip_runtime.h>
#include <hip/hip_bf16.h>

#define HID 64
#define P_BLOCKS 1024  // pass-1 partition blocks (4/CU for latency hiding)
#define MAXB 512       // max coarse buckets (N <= 131072)
#define BCAP 9216      // kp2 LDS bucket capacity (mean 8184 + 11 sigma)
#define TILE 3200      // kp1c per-tile edges (chunk = ceil(E/1024) = 3125 fits)

typedef float v2f __attribute__((ext_vector_type(2)));

// HW fp8 (gfx950: OCP e4m3) conversions — self-consistent pack/unpack.
__device__ inline v2f fp8x2_lo(unsigned u) { return __builtin_amdgcn_cvt_pk_f32_fp8(u, false); }
__device__ inline v2f fp8x2_hi(unsigned u) { return __builtin_amdgcn_cvt_pk_f32_fp8(u, true); }

// t-table (fp8) scale.
#define GSCALE 16.0f
#define GINV 0.0625f
// T1/T2 (fp4 e2m1) scales.
#define GS1 12.0f
#define GI1 (1.0f / 12.0f)
#define GS2 24.0f
#define GI2 (1.0f / 24.0f)
#define WQINV (1.0f / 4095.0f)

// ---------------------------------------------------------------------------
// P1a: per-block LDS histogram of coarse bucket (dst>>8). Bucket-major out.
// ---------------------------------------------------------------------------
__global__ __launch_bounds__(256) void kp1a_hist(const int* __restrict__ dst,
                                                 int* __restrict__ ghist,
                                                 int nE, int B, int chunk) {
    __shared__ int h[MAXB];
    for (int b = threadIdx.x; b < B; b += 256) h[b] = 0;
    __syncthreads();
    int lo = blockIdx.x * chunk;
    int hi = min(nE, lo + chunk);
    for (int i = lo + threadIdx.x; i < hi; i += 256)
        atomicAdd(&h[dst[i] >> 8], 1);
    __syncthreads();
    for (int b = threadIdx.x; b < B; b += 256)
        ghist[(size_t)b * P_BLOCKS + blockIdx.x] = h[b];
}

// ---------------------------------------------------------------------------
// P1b1: per-bucket offset scan — one block per bucket, 1024 entries via int4.
// ---------------------------------------------------------------------------
__global__ __launch_bounds__(256) void kp1b1_scan(const int* __restrict__ ghist,
                                                  int* __restrict__ goff,
                                                  int* __restrict__ btot) {
    __shared__ int wsum[4];
    __shared__ int woff[4];
    int tid = threadIdx.x;
    int lane = tid & 63, wv = tid >> 6;
    int b = blockIdx.x;
    int4 v = ((const int4*)(ghist + (size_t)b * P_BLOCKS))[tid];
    int s = v.x + v.y + v.z + v.w;
    int sc = s;
#pragma unroll
    for (int off = 1; off < 64; off <<= 1) {
        int t = __shfl_up(sc, off);
        if (lane >= off) sc += t;
    }
    if (lane == 63) wsum[wv] = sc;
    __syncthreads();
    if (tid == 0) {
        int acc = 0;
#pragma unroll
        for (int w = 0; w < 4; ++w) { woff[w] = acc; acc += wsum[w]; }
        btot[b] = acc;
    }
    __syncthreads();
    int ex = woff[wv] + sc - s;
    int4 o;
    o.x = ex;
    o.y = ex + v.x;
    o.z = o.y + v.y;
    o.w = o.z + v.z;
    ((int4*)(goff + (size_t)b * P_BLOCKS))[tid] = o;
}

// ---------------------------------------------------------------------------
// P1b2: tiny single-block exclusive scan of btot[0..B-1] -> bstart (B <= 512)
// ---------------------------------------------------------------------------
__global__ __launch_bounds__(512) void kp1b2_scan(const int* __restrict__ btot,
                                                  int* __restrict__ bstart, int B) {
    __shared__ int wsum[8];
    __shared__ int woff[8];
    int tid = threadIdx.x;
    int lane = tid & 63, wv = tid >> 6;
    int tot = (tid < B) ? btot[tid] : 0;
    int sc = tot;
#pragma unroll
    for (int off = 1; off < 64; off <<= 1) {
        int t = __shfl_up(sc, off);
        if (lane >= off) sc += t;
    }
    if (lane == 63) wsum[wv] = sc;
    __syncthreads();
    if (tid == 0) {
        int acc = 0;
#pragma unroll
        for (int w = 0; w < 8; ++w) { woff[w] = acc; acc += wsum[w]; }
        bstart[B] = acc;  // == nE
    }
    __syncthreads();
    if (tid < B) bstart[tid] = woff[wv] + sc - tot;
}

// ---------------------------------------------------------------------------
// P1c: block-level COUNTING SORT into bsw — software write-combining.
// ---------------------------------------------------------------------------
__global__ __launch_bounds__(256) void kp1c_sort(const int* __restrict__ src,
                                                 const int* __restrict__ dst,
                                                 const float* __restrict__ ew,
                                                 const int* __restrict__ goff,
                                                 const int* __restrict__ bstart,
                                                 int2* __restrict__ bsw,
                                                 int nE, int B, int chunk) {
    __shared__ int2 sorted[TILE];
    __shared__ unsigned short bkt[TILE];
    __shared__ int cnt[MAXB];
    __shared__ int lstart[MAXB];
    __shared__ int lcur[MAXB];
    __shared__ int gcur[MAXB];
    __shared__ int wsum[4];
    __shared__ int woff[4];
    int tid = threadIdx.x;
    int lane = tid & 63, wv = tid >> 6;
    for (int b = tid; b < B; b += 256)
        gcur[b] = bstart[b] + goff[(size_t)b * P_BLOCKS + blockIdx.x];
    int lo = blockIdx.x * chunk;
    int hi = min(nE, lo + chunk);
    for (int tb = lo; tb < hi; tb += TILE) {
        int m = min(hi - tb, TILE);
        cnt[tid] = 0;
        cnt[tid + 256] = 0;
        __syncthreads();
        for (int i = tid; i < m; i += 256)
            atomicAdd(&cnt[dst[tb + i] >> 8], 1);
        __syncthreads();
        // pair-wise exclusive scan over 512 bucket counts
        int c0 = cnt[2 * tid], c1 = cnt[2 * tid + 1];
        int s = c0 + c1;
        int sc = s;
#pragma unroll
        for (int off = 1; off < 64; off <<= 1) {
            int t = __shfl_up(sc, off);
            if (lane >= off) sc += t;
        }
        if (lane == 63) wsum[wv] = sc;
        __syncthreads();
        if (tid == 0) {
            int acc = 0;
#pragma unroll
            for (int w = 0; w < 4; ++w) { woff[w] = acc; acc += wsum[w]; }
        }
        __syncthreads();
        int ex = woff[wv] + sc - s;
        lstart[2 * tid] = ex;
        lcur[2 * tid] = ex;
        lstart[2 * tid + 1] = ex + c0;
        lcur[2 * tid + 1] = ex + c0;
        __syncthreads();
        // reorder tile bucket-contiguous into LDS
        for (int i = tid; i < m; i += 256) {
            int d = dst[tb + i];
            int b = d >> 8;
            int pos = atomicAdd(&lcur[b], 1);
            int2 v;
            v.x = src[tb + i] | ((d & 255) << 20);
            v.y = __float_as_int(ew[tb + i]);
            sorted[pos] = v;
            bkt[pos] = (unsigned short)b;
        }
        __syncthreads();
        // coalesced run writes
        for (int i = tid; i < m; i += 256) {
            int b = bkt[i];
            bsw[gcur[b] + (i - lstart[b])] = sorted[i];
        }
        __syncthreads();
        for (int b = tid; b < B; b += 256)
            gcur[b] += lcur[b] - lstart[b];
        __syncthreads();
    }
}

// ---------------------------------------------------------------------------
// P2: per-bucket CSR build + dinv. Emits src(20b) | round(w*4095)<<20.
// ---------------------------------------------------------------------------
__global__ __launch_bounds__(256) void kp2_build(const int2* __restrict__ bsw,
                                                 const int* __restrict__ bstart,
                                                 int* __restrict__ row_start,
                                                 float* __restrict__ dinv,
                                                 unsigned* __restrict__ csr4,
                                                 int n_nodes) {
    __shared__ int2 ebuf[BCAP];
    __shared__ int cnt[256];
    __shared__ float degw[256];
    __shared__ int cur[256];
    __shared__ int wsum[4];
    __shared__ int woff[4];
    int tid = threadIdx.x;
    int lane = tid & 63, wv = tid >> 6;
    int b = blockIdx.x;
    int e0 = bstart[b], e1 = bstart[b + 1];
    int nb = e1 - e0;
    cnt[tid] = 0;
    degw[tid] = 0.0f;
    __syncthreads();
    for (int i = tid; i < nb; i += 256) {
        int2 v = bsw[e0 + i];
        if (i < BCAP) ebuf[i] = v;
        int dlo = (v.x >> 20) & 255;
        atomicAdd(&cnt[dlo], 1);
        atomicAdd(&degw[dlo], __int_as_float(v.y));
    }
    __syncthreads();
    int c = cnt[tid];
    int sc = c;
#pragma unroll
    for (int off = 1; off < 64; off <<= 1) {
        int t = __shfl_up(sc, off);
        if (lane >= off) sc += t;
    }
    if (lane == 63) wsum[wv] = sc;
    __syncthreads();
    if (tid == 0) {
        int acc = 0;
#pragma unroll
        for (int w = 0; w < 4; ++w) { woff[w] = acc; acc += wsum[w]; }
    }
    __syncthreads();
    int ex = woff[wv] + sc - c;
    cur[tid] = ex;
    int node = (b << 8) + tid;
    if (node < n_nodes) {
        row_start[node] = e0 + ex;
        dinv[node] = rsqrtf(fmaxf(degw[tid] + 1.0f, 1e-12f));
    }
    if (b == 0 && tid == 0) row_start[n_nodes] = bstart[gridDim.x];
    __syncthreads();
    for (int i = tid; i < nb; i += 256) {
        int2 v = (i < BCAP) ? ebuf[i] : bsw[e0 + i];   // overflow guard (cold)
        int dlo = (v.x >> 20) & 255;
        int pos = atomicAdd(&cur[dlo], 1);
        float w = __int_as_float(v.y);
        unsigned wq = (unsigned)(w * 4095.0f + 0.5f);
        csr4[e0 + pos] = ((unsigned)v.x & 0xFFFFFu) | (wq << 20);
    }
}

// ---------------------------------------------------------------------------
// K-WT: w~ = W3 @ Wout [64], c0 = b3 . Wout — folds layer-3's matrix away.
// ---------------------------------------------------------------------------
__global__ __launch_bounds__(64) void k_wtilde(const float* __restrict__ W3,
                                               const float* __restrict__ Wout,
                                               const float* __restrict__ b3,
                                               float* __restrict__ wtil,
                                               float* __restrict__ c0) {
    int j = threadIdx.x;
    float s = 0.0f;
    for (int k = 0; k < 64; ++k) s += W3[j * 64 + k] * Wout[k];
    wtil[j] = s;
    if (j == 0) {
        float c = 0.0f;
        for (int k = 0; k < 64; ++k) c += b3[k] * Wout[k];
        c0[0] = c;
    }
}

// ---------------------------------------------------------------------------
// K5-fp4: layer-1 matmul, 8 nodes/wave. T1[n] = fp4((x@W1)*dinv*GS1), 32 B rows.
// ---------------------------------------------------------------------------
__global__ __launch_bounds__(256) void k_mm16f4(const float* __restrict__ in,
                                                const float* __restrict__ W,
                                                const float* __restrict__ dinv,
                                                unsigned* __restrict__ gtab,
                                                int n_nodes) {
    __shared__ float Ws[16 * HID];
    for (int i = threadIdx.x; i < 16 * HID; i += 256) Ws[i] = W[i];
    __syncthreads();
    int lane = threadIdx.x & 63;
    int wid = threadIdx.x >> 6;
    int p = lane & 7;   // dword within row (features 8p..8p+7)
    int q = lane >> 3;  // node within group of 8
    int nGrp = (n_nodes + 7) >> 3;
    for (int grp = blockIdx.x * 4 + wid; grp < nGrp; grp += gridDim.x * 4) {
        int node = grp * 8 + q;
        bool ok = node < n_nodes;
        float xr0 = ok ? in[node * 16 + p] : 0.0f;
        float xr1 = ok ? in[node * 16 + 8 + p] : 0.0f;
        float di = ok ? dinv[node] : 0.0f;
        v2f a01 = {0.0f, 0.0f}, a23 = {0.0f, 0.0f};
        v2f a45 = {0.0f, 0.0f}, a67 = {0.0f, 0.0f};
#pragma unroll
        for (int k = 0; k < 16; ++k) {
            float xv = __shfl((k < 8) ? xr0 : xr1, q * 8 + (k & 7));  // x[node][k]
            const float4* wr = (const float4*)&Ws[k * HID + 8 * p];
            float4 w0 = wr[0], w1 = wr[1];
            v2f wl0 = {w0.x, w0.y}, wl1 = {w0.z, w0.w};
            v2f wl2 = {w1.x, w1.y}, wl3 = {w1.z, w1.w};
            a01 += wl0 * xv; a23 += wl1 * xv; a45 += wl2 * xv; a67 += wl3 * xv;
        }
        float sc = di * GS1;
        unsigned pk = __builtin_amdgcn_cvt_scalef32_pk_fp4_f32(0u, a01.x * sc, a01.y * sc, 1.0f, 0);
        pk = __builtin_amdgcn_cvt_scalef32_pk_fp4_f32(pk, a23.x * sc, a23.y * sc, 1.0f, 1);
        pk = __builtin_amdgcn_cvt_scalef32_pk_fp4_f32(pk, a45.x * sc, a45.y * sc, 1.0f, 2);
        pk = __builtin_amdgcn_cvt_scalef32_pk_fp4_f32(pk, a67.x * sc, a67.y * sc, 1.0f, 3);
        if (ok) gtab[(size_t)node * 8 + p] = pk;
    }
}

// ---------------------------------------------------------------------------
// K6-fp4 (R10): R5 body, but each wave processes 4 CONTIGUOUS nodes
//     sequentially (#pragma unroll 1) — blocks 25000 -> 6250. Single-variable
//     test of the block-turnover-rate theory (all agg variants pinned at
//     ~270-287 blocks/us across R2-R9). Locality and VGPR preserved.
//     OUT4=1: epilogue = sigmoid + @W2 -> fp4 table out.
//     OUT4=0: epilogue = sigmoid + dot(w~) -> fp8 byte (t-table).
// ---------------------------------------------------------------------------
template <int OUT4>
__global__ __launch_bounds__(256) void k_agg4(const unsigned* __restrict__ g4,
                                              const float* __restrict__ bias,
                                              const float* __restrict__ dinv,
                                              const int* __restrict__ row_start,
                                              const unsigned* __restrict__ csr4,
                                              const float* __restrict__ Wn,
                                              void* __restrict__ outv,
                                              int n_nodes, float ginv_in, float gs_out) {
    int lane = threadIdx.x & 63;
    int wid = threadIdx.x >> 6;
    int p = lane & 7;   // dword within fp4 row (features 8p..8p+7)
    int q = lane >> 3;  // edge slot within group of 8
    int node0 = (blockIdx.x * 4 + wid) * 4;   // 4 contiguous nodes per wave

#pragma unroll 1
    for (int nn = 0; nn < 4; ++nn) {
        int node = node0 + nn;
        if (node >= n_nodes) break;
        float diRaw = dinv[node];

        v2f a01 = {0.0f, 0.0f}, a23 = {0.0f, 0.0f};
        v2f a45 = {0.0f, 0.0f}, a67 = {0.0f, 0.0f};
        {   // self term (weight 1), slot 0 only
            unsigned su = g4[(size_t)node * 8 + p];
            if (q == 0) {
                a01 = __builtin_amdgcn_cvt_scalef32_pk_f32_fp4(su, 1.0f, 0);
                a23 = __builtin_amdgcn_cvt_scalef32_pk_f32_fp4(su, 1.0f, 1);
                a45 = __builtin_amdgcn_cvt_scalef32_pk_f32_fp4(su, 1.0f, 2);
                a67 = __builtin_amdgcn_cvt_scalef32_pk_f32_fp4(su, 1.0f, 3);
            }
        }
        int e0 = row_start[node], e1 = row_start[node + 1];
        for (int base = e0; base < e1; base += 64) {
            int m = min(64, e1 - base);
            unsigned sw = 0;   // src=0, wq=0 -> harmless hot-row gather, weight 0
            if (lane < m) sw = __builtin_nontemporal_load(csr4 + base + lane);
            int ng8 = (m + 7) >> 3;
            int ng84 = (ng8 + 3) & ~3;   // pad to 4 groups (32 edges) per iter
            for (int g0 = 0; g0 < ng84; g0 += 4) {
                int b8 = 8 * g0 + q;
                unsigned vA = __shfl(sw, b8);
                unsigned vB = __shfl(sw, b8 + 8);
                unsigned vC = __shfl(sw, b8 + 16);
                unsigned vD = __shfl(sw, b8 + 24);
                unsigned uA = g4[(vA & 0xFFFFFu) * 8u + p];
                unsigned uB = g4[(vB & 0xFFFFFu) * 8u + p];
                unsigned uC = g4[(vC & 0xFFFFFu) * 8u + p];
                unsigned uD = g4[(vD & 0xFFFFFu) * 8u + p];
                float wA = (float)(vA >> 20) * WQINV;
                float wB = (float)(vB >> 20) * WQINV;
                float wC = (float)(vC >> 20) * WQINV;
                float wD = (float)(vD >> 20) * WQINV;
                a01 += __builtin_amdgcn_cvt_scalef32_pk_f32_fp4(uA, 1.0f, 0) * wA;
                a23 += __builtin_amdgcn_cvt_scalef32_pk_f32_fp4(uA, 1.0f, 1) * wA;
                a45 += __builtin_amdgcn_cvt_scalef32_pk_f32_fp4(uA, 1.0f, 2) * wA;
                a67 += __builtin_amdgcn_cvt_scalef32_pk_f32_fp4(uA, 1.0f, 3) * wA;
                a01 += __builtin_amdgcn_cvt_scalef32_pk_f32_fp4(uB, 1.0f, 0) * wB;
                a23 += __builtin_amdgcn_cvt_scalef32_pk_f32_fp4(uB, 1.0f, 1) * wB;
                a45 += __builtin_amdgcn_cvt_scalef32_pk_f32_fp4(uB, 1.0f, 2) * wB;
                a67 += __builtin_amdgcn_cvt_scalef32_pk_f32_fp4(uB, 1.0f, 3) * wB;
                a01 += __builtin_amdgcn_cvt_scalef32_pk_f32_fp4(uC, 1.0f, 0) * wC;
                a23 += __builtin_amdgcn_cvt_scalef32_pk_f32_fp4(uC, 1.0f, 1) * wC;
                a45 += __builtin_amdgcn_cvt_scalef32_pk_f32_fp4(uC, 1.0f, 2) * wC;
                a67 += __builtin_amdgcn_cvt_scalef32_pk_f32_fp4(uC, 1.0f, 3) * wC;
                a01 += __builtin_amdgcn_cvt_scalef32_pk_f32_fp4(uD, 1.0f, 0) * wD;
                a23 += __builtin_amdgcn_cvt_scalef32_pk_f32_fp4(uD, 1.0f, 1) * wD;
                a45 += __builtin_amdgcn_cvt_scalef32_pk_f32_fp4(uD, 1.0f, 2) * wD;
                a67 += __builtin_amdgcn_cvt_scalef32_pk_f32_fp4(uD, 1.0f, 3) * wD;
            }
        }
        // fold the 8 edge slots
        float a[8] = {a01.x, a01.y, a23.x, a23.y, a45.x, a45.y, a67.x, a67.y};
#pragma unroll
        for (int i = 0; i < 8; ++i) {
            a[i] += __shfl_xor(a[i], 8);
            a[i] += __shfl_xor(a[i], 16);
            a[i] += __shfl_xor(a[i], 32);
        }
        float di = diRaw * ginv_in;  // undo table prescale
        float4 bv0 = ((const float4*)bias)[2 * p];
        float4 bv1 = ((const float4*)bias)[2 * p + 1];
        a[0] = fmaf(di, a[0], bv0.x); a[1] = fmaf(di, a[1], bv0.y);
        a[2] = fmaf(di, a[2], bv0.z); a[3] = fmaf(di, a[3], bv0.w);
        a[4] = fmaf(di, a[4], bv1.x); a[5] = fmaf(di, a[5], bv1.y);
        a[6] = fmaf(di, a[6], bv1.z); a[7] = fmaf(di, a[7], bv1.w);
        float s[8];
#pragma unroll
        for (int i = 0; i < 8; ++i) s[i] = 1.0f / (1.0f + __expf(-a[i]));

        if (OUT4) {
            const float4* Wg = (const float4*)Wn;
            v2f o01 = {0.0f, 0.0f}, o23 = {0.0f, 0.0f};
            v2f o45 = {0.0f, 0.0f}, o67 = {0.0f, 0.0f};
#pragma unroll
            for (int st = 0; st < 8; ++st) {
                float av = __shfl(s[st], q);           // act[8q+st]
                const float4* wr = Wg + ((8 * q + st) * 16 + 2 * p);
                float4 w0 = wr[0], w1 = wr[1];
                v2f wl0 = {w0.x, w0.y}, wl1 = {w0.z, w0.w};
                v2f wl2 = {w1.x, w1.y}, wl3 = {w1.z, w1.w};
                o01 += wl0 * av; o23 += wl1 * av; o45 += wl2 * av; o67 += wl3 * av;
            }
            float o[8] = {o01.x, o01.y, o23.x, o23.y, o45.x, o45.y, o67.x, o67.y};
#pragma unroll
            for (int i = 0; i < 8; ++i) {
                o[i] += __shfl_xor(o[i], 8);
                o[i] += __shfl_xor(o[i], 16);
                o[i] += __shfl_xor(o[i], 32);
            }
            if (lane < 8) {
                float sc = diRaw * gs_out;
                unsigned pk = __builtin_amdgcn_cvt_scalef32_pk_fp4_f32(0u, o[0] * sc, o[1] * sc, 1.0f, 0);
                pk = __builtin_amdgcn_cvt_scalef32_pk_fp4_f32(pk, o[2] * sc, o[3] * sc, 1.0f, 1);
                pk = __builtin_amdgcn_cvt_scalef32_pk_fp4_f32(pk, o[4] * sc, o[5] * sc, 1.0f, 2);
                pk = __builtin_amdgcn_cvt_scalef32_pk_fp4_f32(pk, o[6] * sc, o[7] * sc, 1.0f, 3);
                __builtin_nontemporal_store(pk, (unsigned*)outv + (size_t)node * 8 + p);
            }
        } else {
            // scalar epilogue: t = dot(s, w~)*dinv -> fp8 byte
            const float4* wt4 = (const float4*)Wn;   // Wn = wtil[64]
            float4 w0 = wt4[2 * p], w1 = wt4[2 * p + 1];
            float local = s[0] * w0.x + s[1] * w0.y + s[2] * w0.z + s[3] * w0.w
                        + s[4] * w1.x + s[5] * w1.y + s[6] * w1.z + s[7] * w1.w;
            local += __shfl_xor(local, 1);
            local += __shfl_xor(local, 2);
            local += __shfl_xor(local, 4);
            if (lane == 0) {
                unsigned pk = __builtin_amdgcn_cvt_pk_fp8_f32(local * diRaw * gs_out, 0.0f, 0, false);
                ((unsigned char*)outv)[node] = (unsigned char)(pk & 0xFFu);
            }
        }
    }
}

// ---------------------------------------------------------------------------
// K-AGG3S (R10): scalar aggregation — wave per node, 4 contiguous nodes/wave.
//     p[node] = c0 + dinv*GINV*( t[node] + sum_e w_e t[src_e] )
// ---------------------------------------------------------------------------
__global__ __launch_bounds__(256) void k_agg3s(const unsigned char* __restrict__ t8,
                                               const int* __restrict__ row_start,
                                               const float* __restrict__ dinv,
                                               const unsigned* __restrict__ csr4,
                                               const float* __restrict__ c0p,
                                               float* __restrict__ p,
                                               int n_nodes) {
    int lane = threadIdx.x & 63;
    int wid = threadIdx.x >> 6;
    int node0 = (blockIdx.x * 4 + wid) * 4;
#pragma unroll 1
    for (int nn = 0; nn < 4; ++nn) {
        int node = node0 + nn;
        if (node >= n_nodes) break;
        int e0 = row_start[node], e1 = row_start[node + 1];
        float acc = 0.0f;
        for (int base = e0; base < e1; base += 64) {
            int i = base + lane;
            unsigned sw = (i < e1) ? __builtin_nontemporal_load(csr4 + i) : 0u;
            float tv = fp8x2_lo((unsigned)t8[sw & 0xFFFFFu]).x;
            acc += (float)(sw >> 20) * tv;   // wq folded; *WQINV at the end
        }
        acc *= WQINV;
#pragma unroll
        for (int off = 32; off; off >>= 1) acc += __shfl_xor(acc, off);
        if (lane == 0) {
            float self = fp8x2_lo((unsigned)t8[node]).x;
            p[node] = fmaf(dinv[node] * GINV, acc + self, c0p[0]);
        }
    }
}

// ---------------------------------------------------------------------------
// K7: segmented pool over sorted batch — one atomic per uniform 64-node wave
// ---------------------------------------------------------------------------
__global__ __launch_bounds__(256) void k_poolseg(const float* __restrict__ p,
                                                 const int* __restrict__ batch,
                                                 float* __restrict__ psum,
                                                 float* __restrict__ pcnt,
                                                 int n_nodes) {
    int lane = threadIdx.x & 63;
    int gw = (blockIdx.x * blockDim.x + threadIdx.x) >> 6;
    int node = gw * 64 + lane;
    bool valid = node < n_nodes;
    float v = valid ? p[node] : 0.0f;
    int g = valid ? batch[node] : -1;
    int g0 = __shfl(g, 0);
    if (__all((g == g0) && valid)) {
#pragma unroll
        for (int off = 32; off; off >>= 1) v += __shfl_xor(v, off);
        if (lane == 0) {
            atomicAdd(&psum[g0], v);
            atomicAdd(&pcnt[g0], 64.0f);
        }
    } else if (valid) {
        atomicAdd(&psum[g], v);
        atomicAdd(&pcnt[g], 1.0f);
    }
}

// K8: final — out[g] = psum[g]/max(pcnt[g],1) + bout
__global__ __launch_bounds__(64) void k_out(const float* __restrict__ psum,
                                            const float* __restrict__ pcnt,
                                            const float* __restrict__ bout,
                                            float* __restrict__ out, int G) {
    int g = threadIdx.x;
    if (g < G) out[g] = psum[g] / fmaxf(pcnt[g], 1.0f) + bout[0];
}

extern "C" void kernel_launch(void* const* d_in, const int* in_sizes, int n_in,
                              void* d_out, int out_size, void* d_ws, size_t ws_size,
                              hipStream_t stream) {
    const float* x    = (const float*)d_in[0];   // [N,16]
    const int*   eidx = (const int*)d_in[1];     // [2,E]
    const float* ew   = (const float*)d_in[2];   // [E]
    const int*   batch= (const int*)d_in[3];     // [N]
    const float* W1   = (const float*)d_in[4];
    const float* b1   = (const float*)d_in[5];
    const float* W2   = (const float*)d_in[6];
    const float* b2   = (const float*)d_in[7];
    const float* W3   = (const float*)d_in[8];
    const float* b3   = (const float*)d_in[9];
    const float* Wout = (const float*)d_in[10];
    const float* bout = (const float*)d_in[11];
    float* out = (float*)d_out;

    const int N = in_sizes[0] / 16;  // 100000
    const int E = in_sizes[2];       // 3200000
    const int G = out_size;          // 64
    const int* src = eidx;
    const int* dst = eidx + E;
    const int B = (N + 255) >> 8;
    const int chunk = (E + P_BLOCKS - 1) / P_BLOCKS;

    size_t off = 0;
    auto carve = [&](size_t bytes) -> void* {
        void* p = (char*)d_ws + off;
        off += (bytes + 255) & ~(size_t)255;
        return p;
    };
    float* psum     = (float*)carve(64 * 4);
    float* pcnt     = (float*)carve(64 * 4);
    size_t zero_bytes = off;                               // only psum/pcnt
    int*   ghist    = (int*)  carve((size_t)B * P_BLOCKS * 4);
    int*   goff     = (int*)  carve((size_t)B * P_BLOCKS * 4);
    int*   btot    = (int*)  carve((size_t)B * 4);
    int*   bstart   = (int*)  carve((size_t)(B + 1) * 4);
    int2*  bsw      = (int2*) carve((size_t)E * 8);
    int*   row_start= (int*)  carve((size_t)(N + 1) * 4);
    unsigned* csr4  = (unsigned*)carve((size_t)E * 4);
    float* dinv     = (float*)carve((size_t)N * 4);
    unsigned* gA    = (unsigned*)carve((size_t)N * HID);   // T1 fp4
    unsigned* gB    = (unsigned*)carve((size_t)N * HID);   // T2 fp4
    float* p        = (float*)carve((size_t)N * 4);        // pooling scalar
    unsigned char* t8 = (unsigned char*)carve((size_t)N + 256);  // fp8 t-table
    float* c0buf    = (float*)carve(256);
    float* wtil     = (float*)carve(64 * 4);               // W3 @ Wout
    (void)ws_size;

    (void)hipMemsetAsync(d_ws, 0, zero_bytes, stream);

    const int aggBlocks = (N + 15) / 16;   // 4 waves x 4 nodes = 16 nodes/block
    const int waveBlocks = ((N + 63) / 64 * 64 + 255) / 256;
    const int mmB4 = (((N + 7) >> 3) + 3) / 4;

    // --- fold W3@Wout (tiny) ---
    k_wtilde<<<1, 64, 0, stream>>>(W3, Wout, b3, wtil, c0buf);

    // --- CSR build: radix partition (counting-sort scatter), no gl atomics ---
    kp1a_hist<<<P_BLOCKS, 256, 0, stream>>>(dst, ghist, E, B, chunk);
    kp1b1_scan<<<B, 256, 0, stream>>>(ghist, goff, btot);
    kp1b2_scan<<<1, 512, 0, stream>>>(btot, bstart, B);
    kp1c_sort<<<P_BLOCKS, 256, 0, stream>>>(src, dst, ew, goff, bstart,
                                            bsw, E, B, chunk);
    kp2_build<<<B, 256, 0, stream>>>(bsw, bstart, row_start, dinv, csr4, N);

    // --- layer 1 matmul -> T1 fp4 (3.2 MB, per-XCD L2 resident) ---
    k_mm16f4<<<mmB4, 256, 0, stream>>>(x, W1, dinv, gA, N);
    // --- agg1 (fp4 gather) + sigmoid + @W2 -> T2 fp4 ---
    k_agg4<1><<<aggBlocks, 256, 0, stream>>>(gA, b1, dinv, row_start, csr4,
                                             W2, (void*)gB, N, GI1, GS2);
    // --- agg2 (fp4 gather) + sigmoid + dot(w~) -> fp8 t-table (100 KB) ---
    k_agg4<0><<<aggBlocks, 256, 0, stream>>>(gB, b2, dinv, row_start, csr4,
                                             wtil, (void*)t8, N, GI2, GSCALE);
    // --- agg3: scalar gather over the hot t-table -> per-node scalar ---
    k_agg3s<<<aggBlocks, 256, 0, stream>>>(t8, row_start, dinv, csr4, c0buf,
                                           p, N);

    // --- segmented mean-pool (sorted batch) + head ---
    k_poolseg<<<waveBlocks, 256, 0, stream>>>(p, batch, psum, pcnt, N);
    k_out<<<1, 64, 0, stream>>>(psum, pcnt, bout, out, G);
}

// Round 11
// 369.146 us; speedup vs baseline: 1.0863x; 1.0863x over previous
//
#include <hip/hip_runtime.h>
#include <hip/hip_bf16.h>

#define HID 64
#define P_BLOCKS 1024  // pass-1 partition blocks (4/CU for latency hiding)
#define MAXB 512       // max coarse buckets (N <= 131072)
#define BCAP 9216      // kp2 LDS bucket capacity (mean 8184 + 11 sigma)
#define TILE 3200      // kp1c per-tile edges (chunk = ceil(E/1024) = 3125 fits)

typedef float v2f __attribute__((ext_vector_type(2)));

// HW fp8 (gfx950: OCP e4m3) conversions — self-consistent pack/unpack.
__device__ inline v2f fp8x2_lo(unsigned u) { return __builtin_amdgcn_cvt_pk_f32_fp8(u, false); }
__device__ inline v2f fp8x2_hi(unsigned u) { return __builtin_amdgcn_cvt_pk_f32_fp8(u, true); }

// t-table (fp8) scale.
#define GSCALE 16.0f
#define GINV 0.0625f
// T1/T2 (fp4 e2m1) scales.
#define GS1 12.0f
#define GI1 (1.0f / 12.0f)
#define GS2 24.0f
#define GI2 (1.0f / 24.0f)
#define WQINV (1.0f / 4095.0f)

// ---------------------------------------------------------------------------
// P1a: per-block LDS histogram of coarse bucket (dst>>8). Bucket-major out.
// ---------------------------------------------------------------------------
__global__ __launch_bounds__(256) void kp1a_hist(const int* __restrict__ dst,
                                                 int* __restrict__ ghist,
                                                 int nE, int B, int chunk) {
    __shared__ int h[MAXB];
    for (int b = threadIdx.x; b < B; b += 256) h[b] = 0;
    __syncthreads();
    int lo = blockIdx.x * chunk;
    int hi = min(nE, lo + chunk);
    for (int i = lo + threadIdx.x; i < hi; i += 256)
        atomicAdd(&h[dst[i] >> 8], 1);
    __syncthreads();
    for (int b = threadIdx.x; b < B; b += 256)
        ghist[(size_t)b * P_BLOCKS + blockIdx.x] = h[b];
}

// ---------------------------------------------------------------------------
// P1b1: per-bucket offset scan — one block per bucket, 1024 entries via int4.
// ---------------------------------------------------------------------------
__global__ __launch_bounds__(256) void kp1b1_scan(const int* __restrict__ ghist,
                                                  int* __restrict__ goff,
                                                  int* __restrict__ btot) {
    __shared__ int wsum[4];
    __shared__ int woff[4];
    int tid = threadIdx.x;
    int lane = tid & 63, wv = tid >> 6;
    int b = blockIdx.x;
    int4 v = ((const int4*)(ghist + (size_t)b * P_BLOCKS))[tid];
    int s = v.x + v.y + v.z + v.w;
    int sc = s;
#pragma unroll
    for (int off = 1; off < 64; off <<= 1) {
        int t = __shfl_up(sc, off);
        if (lane >= off) sc += t;
    }
    if (lane == 63) wsum[wv] = sc;
    __syncthreads();
    if (tid == 0) {
        int acc = 0;
#pragma unroll
        for (int w = 0; w < 4; ++w) { woff[w] = acc; acc += wsum[w]; }
        btot[b] = acc;
    }
    __syncthreads();
    int ex = woff[wv] + sc - s;
    int4 o;
    o.x = ex;
    o.y = ex + v.x;
    o.z = o.y + v.y;
    o.w = o.z + v.z;
    ((int4*)(goff + (size_t)b * P_BLOCKS))[tid] = o;
}

// ---------------------------------------------------------------------------
// P1b2: tiny single-block exclusive scan of btot[0..B-1] -> bstart (B <= 512)
// ---------------------------------------------------------------------------
__global__ __launch_bounds__(512) void kp1b2_scan(const int* __restrict__ btot,
                                                  int* __restrict__ bstart, int B) {
    __shared__ int wsum[8];
    __shared__ int woff[8];
    int tid = threadIdx.x;
    int lane = tid & 63, wv = tid >> 6;
    int tot = (tid < B) ? btot[tid] : 0;
    int sc = tot;
#pragma unroll
    for (int off = 1; off < 64; off <<= 1) {
        int t = __shfl_up(sc, off);
        if (lane >= off) sc += t;
    }
    if (lane == 63) wsum[wv] = sc;
    __syncthreads();
    if (tid == 0) {
        int acc = 0;
#pragma unroll
        for (int w = 0; w < 8; ++w) { woff[w] = acc; acc += wsum[w]; }
        bstart[B] = acc;  // == nE
    }
    __syncthreads();
    if (tid < B) bstart[tid] = woff[wv] + sc - tot;
}

// ---------------------------------------------------------------------------
// P1c: block-level COUNTING SORT into bsw — software write-combining.
// ---------------------------------------------------------------------------
__global__ __launch_bounds__(256) void kp1c_sort(const int* __restrict__ src,
                                                 const int* __restrict__ dst,
                                                 const float* __restrict__ ew,
                                                 const int* __restrict__ goff,
                                                 const int* __restrict__ bstart,
                                                 int2* __restrict__ bsw,
                                                 int nE, int B, int chunk) {
    __shared__ int2 sorted[TILE];
    __shared__ unsigned short bkt[TILE];
    __shared__ int cnt[MAXB];
    __shared__ int lstart[MAXB];
    __shared__ int lcur[MAXB];
    __shared__ int gcur[MAXB];
    __shared__ int wsum[4];
    __shared__ int woff[4];
    int tid = threadIdx.x;
    int lane = tid & 63, wv = tid >> 6;
    for (int b = tid; b < B; b += 256)
        gcur[b] = bstart[b] + goff[(size_t)b * P_BLOCKS + blockIdx.x];
    int lo = blockIdx.x * chunk;
    int hi = min(nE, lo + chunk);
    for (int tb = lo; tb < hi; tb += TILE) {
        int m = min(hi - tb, TILE);
        cnt[tid] = 0;
        cnt[tid + 256] = 0;
        __syncthreads();
        for (int i = tid; i < m; i += 256)
            atomicAdd(&cnt[dst[tb + i] >> 8], 1);
        __syncthreads();
        // pair-wise exclusive scan over 512 bucket counts
        int c0 = cnt[2 * tid], c1 = cnt[2 * tid + 1];
        int s = c0 + c1;
        int sc = s;
#pragma unroll
        for (int off = 1; off < 64; off <<= 1) {
            int t = __shfl_up(sc, off);
            if (lane >= off) sc += t;
        }
        if (lane == 63) wsum[wv] = sc;
        __syncthreads();
        if (tid == 0) {
            int acc = 0;
#pragma unroll
            for (int w = 0; w < 4; ++w) { woff[w] = acc; acc += wsum[w]; }
        }
        __syncthreads();
        int ex = woff[wv] + sc - s;
        lstart[2 * tid] = ex;
        lcur[2 * tid] = ex;
        lstart[2 * tid + 1] = ex + c0;
        lcur[2 * tid + 1] = ex + c0;
        __syncthreads();
        // reorder tile bucket-contiguous into LDS
        for (int i = tid; i < m; i += 256) {
            int d = dst[tb + i];
            int b = d >> 8;
            int pos = atomicAdd(&lcur[b], 1);
            int2 v;
            v.x = src[tb + i] | ((d & 255) << 20);
            v.y = __float_as_int(ew[tb + i]);
            sorted[pos] = v;
            bkt[pos] = (unsigned short)b;
        }
        __syncthreads();
        // coalesced run writes
        for (int i = tid; i < m; i += 256) {
            int b = bkt[i];
            bsw[gcur[b] + (i - lstart[b])] = sorted[i];
        }
        __syncthreads();
        for (int b = tid; b < B; b += 256)
            gcur[b] += lcur[b] - lstart[b];
        __syncthreads();
    }
}

// ---------------------------------------------------------------------------
// P2: per-bucket CSR build + dinv. Emits src(20b) | round(w*4095)<<20.
// ---------------------------------------------------------------------------
__global__ __launch_bounds__(256) void kp2_build(const int2* __restrict__ bsw,
                                                 const int* __restrict__ bstart,
                                                 int* __restrict__ row_start,
                                                 float* __restrict__ dinv,
                                                 unsigned* __restrict__ csr4,
                                                 int n_nodes) {
    __shared__ int2 ebuf[BCAP];
    __shared__ int cnt[256];
    __shared__ float degw[256];
    __shared__ int cur[256];
    __shared__ int wsum[4];
    __shared__ int woff[4];
    int tid = threadIdx.x;
    int lane = tid & 63, wv = tid >> 6;
    int b = blockIdx.x;
    int e0 = bstart[b], e1 = bstart[b + 1];
    int nb = e1 - e0;
    cnt[tid] = 0;
    degw[tid] = 0.0f;
    __syncthreads();
    for (int i = tid; i < nb; i += 256) {
        int2 v = bsw[e0 + i];
        if (i < BCAP) ebuf[i] = v;
        int dlo = (v.x >> 20) & 255;
        atomicAdd(&cnt[dlo], 1);
        atomicAdd(&degw[dlo], __int_as_float(v.y));
    }
    __syncthreads();
    int c = cnt[tid];
    int sc = c;
#pragma unroll
    for (int off = 1; off < 64; off <<= 1) {
        int t = __shfl_up(sc, off);
        if (lane >= off) sc += t;
    }
    if (lane == 63) wsum[wv] = sc;
    __syncthreads();
    if (tid == 0) {
        int acc = 0;
#pragma unroll
        for (int w = 0; w < 4; ++w) { woff[w] = acc; acc += wsum[w]; }
    }
    __syncthreads();
    int ex = woff[wv] + sc - c;
    cur[tid] = ex;
    int node = (b << 8) + tid;
    if (node < n_nodes) {
        row_start[node] = e0 + ex;
        dinv[node] = rsqrtf(fmaxf(degw[tid] + 1.0f, 1e-12f));
    }
    if (b == 0 && tid == 0) row_start[n_nodes] = bstart[gridDim.x];
    __syncthreads();
    for (int i = tid; i < nb; i += 256) {
        int2 v = (i < BCAP) ? ebuf[i] : bsw[e0 + i];   // overflow guard (cold)
        int dlo = (v.x >> 20) & 255;
        int pos = atomicAdd(&cur[dlo], 1);
        float w = __int_as_float(v.y);
        unsigned wq = (unsigned)(w * 4095.0f + 0.5f);
        csr4[e0 + pos] = ((unsigned)v.x & 0xFFFFFu) | (wq << 20);
    }
}

// ---------------------------------------------------------------------------
// K-WT: w~ = W3 @ Wout [64], c0 = b3 . Wout — folds layer-3's matrix away.
// ---------------------------------------------------------------------------
__global__ __launch_bounds__(64) void k_wtilde(const float* __restrict__ W3,
                                               const float* __restrict__ Wout,
                                               const float* __restrict__ b3,
                                               float* __restrict__ wtil,
                                               float* __restrict__ c0) {
    int j = threadIdx.x;
    float s = 0.0f;
    for (int k = 0; k < 64; ++k) s += W3[j * 64 + k] * Wout[k];
    wtil[j] = s;
    if (j == 0) {
        float c = 0.0f;
        for (int k = 0; k < 64; ++k) c += b3[k] * Wout[k];
        c0[0] = c;
    }
}

// ---------------------------------------------------------------------------
// K5-fp4: layer-1 matmul, 8 nodes/wave. T1[n] = fp4((x@W1)*dinv*GS1), 32 B rows.
// ---------------------------------------------------------------------------
__global__ __launch_bounds__(256) void k_mm16f4(const float* __restrict__ in,
                                                const float* __restrict__ W,
                                                const float* __restrict__ dinv,
                                                unsigned* __restrict__ gtab,
                                                int n_nodes) {
    __shared__ float Ws[16 * HID];
    for (int i = threadIdx.x; i < 16 * HID; i += 256) Ws[i] = W[i];
    __syncthreads();
    int lane = threadIdx.x & 63;
    int wid = threadIdx.x >> 6;
    int p = lane & 7;   // dword within row (features 8p..8p+7)
    int q = lane >> 3;  // node within group of 8
    int nGrp = (n_nodes + 7) >> 3;
    for (int grp = blockIdx.x * 4 + wid; grp < nGrp; grp += gridDim.x * 4) {
        int node = grp * 8 + q;
        bool ok = node < n_nodes;
        float xr0 = ok ? in[node * 16 + p] : 0.0f;
        float xr1 = ok ? in[node * 16 + 8 + p] : 0.0f;
        float di = ok ? dinv[node] : 0.0f;
        v2f a01 = {0.0f, 0.0f}, a23 = {0.0f, 0.0f};
        v2f a45 = {0.0f, 0.0f}, a67 = {0.0f, 0.0f};
#pragma unroll
        for (int k = 0; k < 16; ++k) {
            float xv = __shfl((k < 8) ? xr0 : xr1, q * 8 + (k & 7));  // x[node][k]
            const float4* wr = (const float4*)&Ws[k * HID + 8 * p];
            float4 w0 = wr[0], w1 = wr[1];
            v2f wl0 = {w0.x, w0.y}, wl1 = {w0.z, w0.w};
            v2f wl2 = {w1.x, w1.y}, wl3 = {w1.z, w1.w};
            a01 += wl0 * xv; a23 += wl1 * xv; a45 += wl2 * xv; a67 += wl3 * xv;
        }
        float sc = di * GS1;
        unsigned pk = __builtin_amdgcn_cvt_scalef32_pk_fp4_f32(0u, a01.x * sc, a01.y * sc, 1.0f, 0);
        pk = __builtin_amdgcn_cvt_scalef32_pk_fp4_f32(pk, a23.x * sc, a23.y * sc, 1.0f, 1);
        pk = __builtin_amdgcn_cvt_scalef32_pk_fp4_f32(pk, a45.x * sc, a45.y * sc, 1.0f, 2);
        pk = __builtin_amdgcn_cvt_scalef32_pk_fp4_f32(pk, a67.x * sc, a67.y * sc, 1.0f, 3);
        if (ok) gtab[(size_t)node * 8 + p] = pk;
    }
}

// ---------------------------------------------------------------------------
// Epilogue for one node (fold + bias + sigmoid + OUT4-specific tail).
// ---------------------------------------------------------------------------
template <int OUT4>
__device__ __forceinline__ void agg_epi(int node, int lane, int p, int q,
                                        float diRaw,
                                        v2f a01, v2f a23, v2f a45, v2f a67,
                                        const float* __restrict__ bias,
                                        const float* __restrict__ Wn,
                                        void* __restrict__ outv,
                                        float ginv_in, float gs_out) {
    float a[8] = {a01.x, a01.y, a23.x, a23.y, a45.x, a45.y, a67.x, a67.y};
#pragma unroll
    for (int i = 0; i < 8; ++i) {
        a[i] += __shfl_xor(a[i], 8);
        a[i] += __shfl_xor(a[i], 16);
        a[i] += __shfl_xor(a[i], 32);
    }
    float di = diRaw * ginv_in;  // undo table prescale
    float4 bv0 = ((const float4*)bias)[2 * p];
    float4 bv1 = ((const float4*)bias)[2 * p + 1];
    a[0] = fmaf(di, a[0], bv0.x); a[1] = fmaf(di, a[1], bv0.y);
    a[2] = fmaf(di, a[2], bv0.z); a[3] = fmaf(di, a[3], bv0.w);
    a[4] = fmaf(di, a[4], bv1.x); a[5] = fmaf(di, a[5], bv1.y);
    a[6] = fmaf(di, a[6], bv1.z); a[7] = fmaf(di, a[7], bv1.w);
    float s[8];
#pragma unroll
    for (int i = 0; i < 8; ++i) s[i] = 1.0f / (1.0f + __expf(-a[i]));

    if (OUT4) {
        const float4* Wg = (const float4*)Wn;
        v2f o01 = {0.0f, 0.0f}, o23 = {0.0f, 0.0f};
        v2f o45 = {0.0f, 0.0f}, o67 = {0.0f, 0.0f};
#pragma unroll
        for (int st = 0; st < 8; ++st) {
            float av = __shfl(s[st], q);           // act[8q+st] (lane q holds it)
            const float4* wr = Wg + ((8 * q + st) * 16 + 2 * p);
            float4 w0 = wr[0], w1 = wr[1];
            v2f wl0 = {w0.x, w0.y}, wl1 = {w0.z, w0.w};
            v2f wl2 = {w1.x, w1.y}, wl3 = {w1.z, w1.w};
            o01 += wl0 * av; o23 += wl1 * av; o45 += wl2 * av; o67 += wl3 * av;
        }
        float o[8] = {o01.x, o01.y, o23.x, o23.y, o45.x, o45.y, o67.x, o67.y};
#pragma unroll
        for (int i = 0; i < 8; ++i) {
            o[i] += __shfl_xor(o[i], 8);
            o[i] += __shfl_xor(o[i], 16);
            o[i] += __shfl_xor(o[i], 32);
        }
        if (lane < 8) {   // q==0, p=lane: one dword-group of the output row
            float sc = diRaw * gs_out;
            unsigned pk = __builtin_amdgcn_cvt_scalef32_pk_fp4_f32(0u, o[0] * sc, o[1] * sc, 1.0f, 0);
            pk = __builtin_amdgcn_cvt_scalef32_pk_fp4_f32(pk, o[2] * sc, o[3] * sc, 1.0f, 1);
            pk = __builtin_amdgcn_cvt_scalef32_pk_fp4_f32(pk, o[4] * sc, o[5] * sc, 1.0f, 2);
            pk = __builtin_amdgcn_cvt_scalef32_pk_fp4_f32(pk, o[6] * sc, o[7] * sc, 1.0f, 3);
            __builtin_nontemporal_store(pk, (unsigned*)outv + (size_t)node * 8 + p);
        }
    } else {
        // scalar epilogue: t = dot(s, w~)*dinv -> fp8 byte
        const float4* wt4 = (const float4*)Wn;   // Wn = wtil[64]
        float4 w0 = wt4[2 * p], w1 = wt4[2 * p + 1];
        float local = s[0] * w0.x + s[1] * w0.y + s[2] * w0.z + s[3] * w0.w
                    + s[4] * w1.x + s[5] * w1.y + s[6] * w1.z + s[7] * w1.w;
        local += __shfl_xor(local, 1);
        local += __shfl_xor(local, 2);
        local += __shfl_xor(local, 4);
        if (lane == 0) {
            unsigned pk = __builtin_amdgcn_cvt_pk_fp8_f32(local * diRaw * gs_out, 0.0f, 0, false);
            ((unsigned char*)outv)[node] = (unsigned char)(pk & 0xFFu);
        }
    }
}

#define ACC_FP4(u, w, a01, a23, a45, a67)                                   \
    a01 += __builtin_amdgcn_cvt_scalef32_pk_f32_fp4(u, 1.0f, 0) * (w);      \
    a23 += __builtin_amdgcn_cvt_scalef32_pk_f32_fp4(u, 1.0f, 1) * (w);      \
    a45 += __builtin_amdgcn_cvt_scalef32_pk_f32_fp4(u, 1.0f, 2) * (w);      \
    a67 += __builtin_amdgcn_cvt_scalef32_pk_f32_fp4(u, 1.0f, 3) * (w);

// ---------------------------------------------------------------------------
// K6-fp4 (R11): TWO NODES PER WAVE, INTERLEAVED — node-level ILP. R2-R10
//     evidence: per-wave VMEM chain fully serialized (~11800 cyc/node); the
//     fix is overlapping two nodes' chains (8 gathers in flight, both csr
//     streams loaded together). Bodies/math identical to the R5-proven form.
// ---------------------------------------------------------------------------
template <int OUT4>
__global__ __launch_bounds__(256) void k_agg4(const unsigned* __restrict__ g4,
                                              const float* __restrict__ bias,
                                              const float* __restrict__ dinv,
                                              const int* __restrict__ row_start,
                                              const unsigned* __restrict__ csr4,
                                              const float* __restrict__ Wn,
                                              void* __restrict__ outv,
                                              int n_nodes, float ginv_in, float gs_out) {
    int lane = threadIdx.x & 63;
    int wid = threadIdx.x >> 6;
    int p = lane & 7;   // dword within fp4 row (features 8p..8p+7)
    int q = lane >> 3;  // edge slot within group of 8
    int nodeA = (blockIdx.x * 4 + wid) * 2;
    int nodeB = nodeA + 1;
    if (nodeA >= n_nodes) return;
    bool hasB = nodeB < n_nodes;

    // issue all per-node metadata loads up front (overlapped)
    float diA = dinv[nodeA];
    float diB = hasB ? dinv[nodeB] : 0.0f;
    int rs0 = row_start[nodeA];
    int rs1 = row_start[nodeA + 1];
    int rs2 = hasB ? row_start[nodeA + 2] : rs1;
    unsigned suA = g4[(size_t)nodeA * 8 + p];
    unsigned suB = hasB ? g4[(size_t)nodeB * 8 + p] : 0u;

    v2f aA01 = {0, 0}, aA23 = {0, 0}, aA45 = {0, 0}, aA67 = {0, 0};
    v2f aB01 = {0, 0}, aB23 = {0, 0}, aB45 = {0, 0}, aB67 = {0, 0};
    if (q == 0) {
        aA01 = __builtin_amdgcn_cvt_scalef32_pk_f32_fp4(suA, 1.0f, 0);
        aA23 = __builtin_amdgcn_cvt_scalef32_pk_f32_fp4(suA, 1.0f, 1);
        aA45 = __builtin_amdgcn_cvt_scalef32_pk_f32_fp4(suA, 1.0f, 2);
        aA67 = __builtin_amdgcn_cvt_scalef32_pk_f32_fp4(suA, 1.0f, 3);
        aB01 = __builtin_amdgcn_cvt_scalef32_pk_f32_fp4(suB, 1.0f, 0);
        aB23 = __builtin_amdgcn_cvt_scalef32_pk_f32_fp4(suB, 1.0f, 1);
        aB45 = __builtin_amdgcn_cvt_scalef32_pk_f32_fp4(suB, 1.0f, 2);
        aB67 = __builtin_amdgcn_cvt_scalef32_pk_f32_fp4(suB, 1.0f, 3);
    }
    int baseA = rs0, e1A = rs1;
    int baseB = rs1, e1B = rs2;
    while (baseA < e1A || baseB < e1B) {
        int mA = (baseA < e1A) ? min(64, e1A - baseA) : 0;
        int mB = (baseB < e1B) ? min(64, e1B - baseB) : 0;
        unsigned swA = 0, swB = 0;   // sw=0 -> row0, weight0: harmless pad
        if (lane < mA) swA = __builtin_nontemporal_load(csr4 + baseA + lane);
        if (lane < mB) swB = __builtin_nontemporal_load(csr4 + baseB + lane);
        int ngA = (((mA + 7) >> 3) + 3) & ~3;
        int ngB = (((mB + 7) >> 3) + 3) & ~3;
        int ng = max(ngA, ngB);
        for (int g0 = 0; g0 < ng; g0 += 4) {
            int b8 = 8 * g0 + q;
            unsigned vA0 = __shfl(swA, b8),      vB0 = __shfl(swA, b8 + 8);
            unsigned vC0 = __shfl(swA, b8 + 16), vD0 = __shfl(swA, b8 + 24);
            unsigned vA1 = __shfl(swB, b8),      vB1 = __shfl(swB, b8 + 8);
            unsigned vC1 = __shfl(swB, b8 + 16), vD1 = __shfl(swB, b8 + 24);
            // 8 gathers in flight
            unsigned uA0 = g4[(vA0 & 0xFFFFFu) * 8u + p];
            unsigned uB0 = g4[(vB0 & 0xFFFFFu) * 8u + p];
            unsigned uC0 = g4[(vC0 & 0xFFFFFu) * 8u + p];
            unsigned uD0 = g4[(vD0 & 0xFFFFFu) * 8u + p];
            unsigned uA1 = g4[(vA1 & 0xFFFFFu) * 8u + p];
            unsigned uB1 = g4[(vB1 & 0xFFFFFu) * 8u + p];
            unsigned uC1 = g4[(vC1 & 0xFFFFFu) * 8u + p];
            unsigned uD1 = g4[(vD1 & 0xFFFFFu) * 8u + p];
            float wA0 = (float)(vA0 >> 20) * WQINV;
            float wB0 = (float)(vB0 >> 20) * WQINV;
            float wC0 = (float)(vC0 >> 20) * WQINV;
            float wD0 = (float)(vD0 >> 20) * WQINV;
            float wA1 = (float)(vA1 >> 20) * WQINV;
            float wB1 = (float)(vB1 >> 20) * WQINV;
            float wC1 = (float)(vC1 >> 20) * WQINV;
            float wD1 = (float)(vD1 >> 20) * WQINV;
            ACC_FP4(uA0, wA0, aA01, aA23, aA45, aA67)
            ACC_FP4(uB0, wB0, aA01, aA23, aA45, aA67)
            ACC_FP4(uC0, wC0, aA01, aA23, aA45, aA67)
            ACC_FP4(uD0, wD0, aA01, aA23, aA45, aA67)
            ACC_FP4(uA1, wA1, aB01, aB23, aB45, aB67)
            ACC_FP4(uB1, wB1, aB01, aB23, aB45, aB67)
            ACC_FP4(uC1, wC1, aB01, aB23, aB45, aB67)
            ACC_FP4(uD1, wD1, aB01, aB23, aB45, aB67)
        }
        baseA += 64;
        baseB += 64;
    }
    agg_epi<OUT4>(nodeA, lane, p, q, diA, aA01, aA23, aA45, aA67,
                  bias, Wn, outv, ginv_in, gs_out);
    if (hasB)
        agg_epi<OUT4>(nodeB, lane, p, q, diB, aB01, aB23, aB45, aB67,
                      bias, Wn, outv, ginv_in, gs_out);
}

// ---------------------------------------------------------------------------
// K-AGG3S (R11): scalar aggregation — 2 nodes per wave, interleaved.
//     p[node] = c0 + dinv*GINV*( t[node] + sum_e w_e t[src_e] )
// ---------------------------------------------------------------------------
__global__ __launch_bounds__(256) void k_agg3s(const unsigned char* __restrict__ t8,
                                               const int* __restrict__ row_start,
                                               const float* __restrict__ dinv,
                                               const unsigned* __restrict__ csr4,
                                               const float* __restrict__ c0p,
                                               float* __restrict__ p,
                                               int n_nodes) {
    int lane = threadIdx.x & 63;
    int wid = threadIdx.x >> 6;
    int nodeA = (blockIdx.x * 4 + wid) * 2;
    int nodeB = nodeA + 1;
    if (nodeA >= n_nodes) return;
    bool hasB = nodeB < n_nodes;
    int rs0 = row_start[nodeA];
    int rs1 = row_start[nodeA + 1];
    int rs2 = hasB ? row_start[nodeA + 2] : rs1;
    float accA = 0.0f, accB = 0.0f;
    int baseA = rs0, e1A = rs1;
    int baseB = rs1, e1B = rs2;
    while (baseA < e1A || baseB < e1B) {
        int iA = baseA + lane, iB = baseB + lane;
        unsigned swA = (baseA < e1A && iA < e1A)
                           ? __builtin_nontemporal_load(csr4 + iA) : 0u;
        unsigned swB = (baseB < e1B && iB < e1B)
                           ? __builtin_nontemporal_load(csr4 + iB) : 0u;
        float tA = fp8x2_lo((unsigned)t8[swA & 0xFFFFFu]).x;  // 2 gathers
        float tB = fp8x2_lo((unsigned)t8[swB & 0xFFFFFu]).x;  // in flight
        accA += (float)(swA >> 20) * tA;
        accB += (float)(swB >> 20) * tB;
        baseA += 64;
        baseB += 64;
    }
    accA *= WQINV;
    accB *= WQINV;
#pragma unroll
    for (int off = 32; off; off >>= 1) {
        accA += __shfl_xor(accA, off);
        accB += __shfl_xor(accB, off);
    }
    if (lane == 0) {
        float c0 = c0p[0];
        float selfA = fp8x2_lo((unsigned)t8[nodeA]).x;
        p[nodeA] = fmaf(dinv[nodeA] * GINV, accA + selfA, c0);
        if (hasB) {
            float selfB = fp8x2_lo((unsigned)t8[nodeB]).x;
            p[nodeB] = fmaf(dinv[nodeB] * GINV, accB + selfB, c0);
        }
    }
}

// ---------------------------------------------------------------------------
// K7: segmented pool over sorted batch — one atomic per uniform 64-node wave
// ---------------------------------------------------------------------------
__global__ __launch_bounds__(256) void k_poolseg(const float* __restrict__ p,
                                                 const int* __restrict__ batch,
                                                 float* __restrict__ psum,
                                                 float* __restrict__ pcnt,
                                                 int n_nodes) {
    int lane = threadIdx.x & 63;
    int gw = (blockIdx.x * blockDim.x + threadIdx.x) >> 6;
    int node = gw * 64 + lane;
    bool valid = node < n_nodes;
    float v = valid ? p[node] : 0.0f;
    int g = valid ? batch[node] : -1;
    int g0 = __shfl(g, 0);
    if (__all((g == g0) && valid)) {
#pragma unroll
        for (int off = 32; off; off >>= 1) v += __shfl_xor(v, off);
        if (lane == 0) {
            atomicAdd(&psum[g0], v);
            atomicAdd(&pcnt[g0], 64.0f);
        }
    } else if (valid) {
        atomicAdd(&psum[g], v);
        atomicAdd(&pcnt[g], 1.0f);
    }
}

// K8: final — out[g] = psum[g]/max(pcnt[g],1) + bout
__global__ __launch_bounds__(64) void k_out(const float* __restrict__ psum,
                                            const float* __restrict__ pcnt,
                                            const float* __restrict__ bout,
                                            float* __restrict__ out, int G) {
    int g = threadIdx.x;
    if (g < G) out[g] = psum[g] / fmaxf(pcnt[g], 1.0f) + bout[0];
}

extern "C" void kernel_launch(void* const* d_in, const int* in_sizes, int n_in,
                              void* d_out, int out_size, void* d_ws, size_t ws_size,
                              hipStream_t stream) {
    const float* x    = (const float*)d_in[0];   // [N,16]
    const int*   eidx = (const int*)d_in[1];     // [2,E]
    const float* ew   = (const float*)d_in[2];   // [E]
    const int*   batch= (const int*)d_in[3];     // [N]
    const float* W1   = (const float*)d_in[4];
    const float* b1   = (const float*)d_in[5];
    const float* W2   = (const float*)d_in[6];
    const float* b2   = (const float*)d_in[7];
    const float* W3   = (const float*)d_in[8];
    const float* b3   = (const float*)d_in[9];
    const float* Wout = (const float*)d_in[10];
    const float* bout = (const float*)d_in[11];
    float* out = (float*)d_out;

    const int N = in_sizes[0] / 16;  // 100000
    const int E = in_sizes[2];       // 3200000
    const int G = out_size;          // 64
    const int* src = eidx;
    const int* dst = eidx + E;
    const int B = (N + 255) >> 8;
    const int chunk = (E + P_BLOCKS - 1) / P_BLOCKS;

    size_t off = 0;
    auto carve = [&](size_t bytes) -> void* {
        void* p = (char*)d_ws + off;
        off += (bytes + 255) & ~(size_t)255;
        return p;
    };
    float* psum     = (float*)carve(64 * 4);
    float* pcnt     = (float*)carve(64 * 4);
    size_t zero_bytes = off;                               // only psum/pcnt
    int*   ghist    = (int*)  carve((size_t)B * P_BLOCKS * 4);
    int*   goff     = (int*)  carve((size_t)B * P_BLOCKS * 4);
    int*   btot    = (int*)  carve((size_t)B * 4);
    int*   bstart   = (int*)  carve((size_t)(B + 1) * 4);
    int2*  bsw      = (int2*) carve((size_t)E * 8);
    int*   row_start= (int*)  carve((size_t)(N + 1) * 4);
    unsigned* csr4  = (unsigned*)carve((size_t)E * 4);
    float* dinv     = (float*)carve((size_t)N * 4);
    unsigned* gA    = (unsigned*)carve((size_t)N * HID);   // T1 fp4
    unsigned* gB    = (unsigned*)carve((size_t)N * HID);   // T2 fp4
    float* p        = (float*)carve((size_t)N * 4);        // pooling scalar
    unsigned char* t8 = (unsigned char*)carve((size_t)N + 256);  // fp8 t-table
    float* c0buf    = (float*)carve(256);
    float* wtil     = (float*)carve(64 * 4);               // W3 @ Wout
    (void)ws_size;

    (void)hipMemsetAsync(d_ws, 0, zero_bytes, stream);

    const int aggBlocks = ((N + 1) / 2 + 3) / 4;   // 4 waves x 2 nodes / block
    const int waveBlocks = ((N + 63) / 64 * 64 + 255) / 256;
    const int mmB4 = (((N + 7) >> 3) + 3) / 4;

    // --- fold W3@Wout (tiny) ---
    k_wtilde<<<1, 64, 0, stream>>>(W3, Wout, b3, wtil, c0buf);

    // --- CSR build: radix partition (counting-sort scatter), no gl atomics ---
    kp1a_hist<<<P_BLOCKS, 256, 0, stream>>>(dst, ghist, E, B, chunk);
    kp1b1_scan<<<B, 256, 0, stream>>>(ghist, goff, btot);
    kp1b2_scan<<<1, 512, 0, stream>>>(btot, bstart, B);
    kp1c_sort<<<P_BLOCKS, 256, 0, stream>>>(src, dst, ew, goff, bstart,
                                            bsw, E, B, chunk);
    kp2_build<<<B, 256, 0, stream>>>(bsw, bstart, row_start, dinv, csr4, N);

    // --- layer 1 matmul -> T1 fp4 (3.2 MB, per-XCD L2 resident) ---
    k_mm16f4<<<mmB4, 256, 0, stream>>>(x, W1, dinv, gA, N);
    // --- agg1 (fp4 gather) + sigmoid + @W2 -> T2 fp4 ---
    k_agg4<1><<<aggBlocks, 256, 0, stream>>>(gA, b1, dinv, row_start, csr4,
                                             W2, (void*)gB, N, GI1, GS2);
    // --- agg2 (fp4 gather) + sigmoid + dot(w~) -> fp8 t-table (100 KB) ---
    k_agg4<0><<<aggBlocks, 256, 0, stream>>>(gB, b2, dinv, row_start, csr4,
                                             wtil, (void*)t8, N, GI2, GSCALE);
    // --- agg3: scalar gather over the hot t-table -> per-node scalar ---
    k_agg3s<<<aggBlocks, 256, 0, stream>>>(t8, row_start, dinv, csr4, c0buf,
                                           p, N);

    // --- segmented mean-pool (sorted batch) + head ---
    k_poolseg<<<waveBlocks, 256, 0, stream>>>(p, batch, psum, pcnt, N);
    k_out<<<1, 64, 0, stream>>>(psum, pcnt, bout, out, G);
}